// Round 1
// baseline (9.263 us; speedup 1.0000x reference)
//
#include <hip/hip_runtime.h>
#include <math.h>

// BitwiseOps: out[r,c] = softmax over 65536 (a,b) pairs of 10*(a_emb[r,a]+b_emb[r,b]),
// scattered by c = a^b.  Factorized form:
//   ea[a] = exp(10*(a_emb[r,a]-ma)), eb[b] = exp(10*(b_emb[r,b]-mb))
//   out[r,c] = (sum_a ea[a]*eb[a^c]) / (sum ea * sum eb)
// W1/W2 one-hot tables are never read (op fixed to XOR in the reference).

__global__ __launch_bounds__(1024) void BitwiseOps_62380105007334_kernel(
    const float* __restrict__ a_emb,
    const float* __restrict__ b_emb,
    float* __restrict__ out)
{
    const int r    = blockIdx.x;     // row 0..3
    const int tid  = threadIdx.x;    // 0..1023
    const int lane = tid & 63;
    const int wave = tid >> 6;       // 0..15

    __shared__ float ea[256];
    __shared__ float eb[256];
    __shared__ float wred[16];
    __shared__ float scal[3];        // ma, mb, 1/(sa*sb)
    __shared__ float part[1024];

    // ---- Stage 1: load + per-row max reduce (threads 0..255 -> a, 256..511 -> b)
    float v = -1e30f;
    if (tid < 256)      v = a_emb[r * 256 + tid];
    else if (tid < 512) v = b_emb[r * 256 + (tid - 256)];

    float m = v;
    #pragma unroll
    for (int off = 32; off; off >>= 1) m = fmaxf(m, __shfl_xor(m, off, 64));
    if (lane == 0) wred[wave] = m;
    __syncthreads();
    if (tid == 0) {
        scal[0] = fmaxf(fmaxf(wred[0], wred[1]), fmaxf(wred[2], wred[3]));
        scal[1] = fmaxf(fmaxf(wred[4], wred[5]), fmaxf(wred[6], wred[7]));
    }
    __syncthreads();

    // ---- Stage 2: exp + sum reduce (factorized softmax denominator)
    float e = 0.0f;
    if (tid < 512) {
        const float mm = (tid < 256) ? scal[0] : scal[1];
        e = expf(10.0f * (v - mm));
        if (tid < 256) ea[tid] = e;
        else           eb[tid - 256] = e;
    }
    float s = e;
    #pragma unroll
    for (int off = 32; off; off >>= 1) s += __shfl_xor(s, off, 64);
    if (lane == 0) wred[wave] = s;
    __syncthreads();
    if (tid == 0) {
        const float sa = wred[0] + wred[1] + wred[2] + wred[3];
        const float sb = wred[4] + wred[5] + wred[6] + wred[7];
        scal[2] = 1.0f / (sa * sb);
    }
    __syncthreads();

    // ---- Stage 3: XOR-convolution. thread -> (c = tid&255, partial range p = tid>>8)
    const int c = tid & 255;
    const int p = tid >> 8;          // 0..3, each covers 64 values of a
    const int abase = p * 64;
    float acc = 0.0f;
    #pragma unroll 8
    for (int i = 0; i < 64; ++i) {
        const int a = abase + i;
        acc += ea[a] * eb[a ^ c];    // ea: broadcast; eb: bank-bijective (2 lanes/bank)
    }
    part[tid] = acc;
    __syncthreads();

    if (tid < 256) {
        const float res = (part[tid] + part[tid + 256] + part[tid + 512] + part[tid + 768])
                          * scal[2];
        out[r * 256 + tid] = res;
    }
}

extern "C" void kernel_launch(void* const* d_in, const int* in_sizes, int n_in,
                              void* d_out, int out_size, void* d_ws, size_t ws_size,
                              hipStream_t stream) {
    const float* a_emb = (const float*)d_in[0];
    const float* b_emb = (const float*)d_in[1];
    // d_in[2] = W1, d_in[3] = W2 — one-hot tables, algebraically folded away.
    float* out = (float*)d_out;
    BitwiseOps_62380105007334_kernel<<<4, 1024, 0, stream>>>(a_emb, b_emb, out);
}